// Round 4
// baseline (40.854 us; speedup 1.0000x reference)
//
#include <hip/hip_runtime.h>

#define NUM_POINTS 2048
#define FEAT 512
#define BATCH 32

using v8s = __attribute__((ext_vector_type(8))) short;
using v4f = __attribute__((ext_vector_type(4))) float;

typedef __attribute__((address_space(3))) float lds_f;
typedef const __attribute__((address_space(1))) float gbl_f;

// fp32 -> bf16 round-to-nearest-even
static __device__ __forceinline__ short f2bf(float x) {
  unsigned u = __float_as_uint(x);
  u += 0x7FFFu + ((u >> 16) & 1u);
  return (short)(u >> 16);
}

// Pack glf (fp32 [32][512]) into bf16 MFMA B-fragments in ws (proven R1/R3).
// lane l holds B[k = ks*32 + (l>>4)*8 + j][col = nt*16 + (l&15)], j=0..7
__global__ void build_bfrag(const float* __restrict__ glf, short* __restrict__ frag) {
  int i = blockIdx.x * 256 + threadIdx.x;  // 0..16383
  int j = i & 7;
  int l = (i >> 3) & 63;
  int nt = (i >> 9) & 1;
  int ks = i >> 10;
  int b = nt * 16 + (l & 15);
  int k = ks * 32 + ((l >> 4) << 3) + j;
  frag[i] = f2bf(glf[b * FEAT + k]);
}

// One block per position. Stage the position's full W1 slab (32 rows x 2KB
// = 64KB fp32) into LDS via global_load_lds: every wave instruction reads
// 1KB CONTIGUOUS (fill-kernel pattern). XOR-swizzle (16B-chunk ^= row&7)
// applied on the SOURCE address (linear LDS dest) and on the ds_read side.
// Each wave computes one 16x16 output quadrant (mt=w>>1, nt=w&1).
__global__ void __launch_bounds__(256, 2) fcdec_main(
    const float* __restrict__ W1, const float* __restrict__ b1,
    const float* __restrict__ W2, const float* __restrict__ b2,
    const float* __restrict__ W3, const float* __restrict__ b3,
    const short* __restrict__ bfrag, float* __restrict__ out) {
  __shared__ float tile[32 * FEAT];   // 64 KB
  __shared__ float h1s[32][33];
  __shared__ float h2s[8][33];

  const int t = threadIdx.x;
  const int w = t >> 6;
  const int l = t & 63;
  const int p = blockIdx.x;
  const float* A0 = W1 + (size_t)p * (32u * FEAT);

  // ---- Stage: wave w loads rows w*8 .. w*8+7, 1KB contiguous per instr ----
  #pragma unroll
  for (int i = 0; i < 16; ++i) {
    const int rr = i >> 1;       // row & 7  (w*8 is 8-aligned)
    const int h = i & 1;         // which half-row (1KB)
    const int r = w * 8 + rr;    // tile row 0..31
    // source 16B-chunk = (h*64 + l) ^ rr  (XOR low 3 bits of l)
    gbl_f* src = (gbl_f*)(A0 + (size_t)r * FEAT + ((h * 64 + (l ^ rr)) << 2));
    lds_f* dst = (lds_f*)&tile[r * FEAT + h * 256];
    __builtin_amdgcn_global_load_lds(src, dst, 16, 0, 0);
  }
  __syncthreads();   // drains vmcnt(0): whole tile resident

  // ---- Compute: wave quadrant (mt, nt); K = 512 = 16 MFMA steps ----
  const int mt = w >> 1;
  const int nt = w & 1;
  const int lrow = l & 15;
  const int g = l >> 4;          // 0..3
  const int s = l & 7;           // read-side XOR key (row & 7)
  const int Rbase = (mt * 16 + lrow) * FEAT;

  v4f acc = {};
  #pragma unroll
  for (int ks = 0; ks < 16; ++ks) {
    const int c0 = ks * 8 + g * 2;             // logical 16B-chunk
    float4 f0 = *(const float4*)&tile[Rbase + ((c0 ^ s) << 2)];
    float4 f1 = *(const float4*)&tile[Rbase + (((c0 + 1) ^ s) << 2)];
    v8s a;
    a[0] = f2bf(f0.x); a[1] = f2bf(f0.y); a[2] = f2bf(f0.z); a[3] = f2bf(f0.w);
    a[4] = f2bf(f1.x); a[5] = f2bf(f1.y); a[6] = f2bf(f1.z); a[7] = f2bf(f1.w);
    v8s bv = *(const v8s*)(bfrag + (((ks * 2 + nt) * 64 + l) << 3));
    acc = __builtin_amdgcn_mfma_f32_16x16x32_bf16(a, bv, acc, 0, 0, 0);
  }

  // ---- h1 = acc + b1 -> LDS. C/D: lane l holds C[row=g*4+r][col=l&15] ----
  #pragma unroll
  for (int r4 = 0; r4 < 4; ++r4) {
    const int o = mt * 16 + g * 4 + r4;
    const int b = nt * 16 + lrow;
    h1s[o][b] = acc[r4] + b1[p * 32 + o];
  }
  __syncthreads();

  // ---- Layer 2: 256 threads = 8 outs x 32 batches ----
  {
    const int o8 = t >> 5;
    const int b = t & 31;
    float s2 = b2[p * 8 + o8];
    const float* w2 = W2 + (size_t)(p * 8 + o8) * 32;
    #pragma unroll
    for (int i = 0; i < 32; ++i) s2 += w2[i] * h1s[i][b];
    h2s[o8][b] = s2;
  }
  __syncthreads();

  // ---- Layer 3: 32 threads, 3 outputs each ----
  if (t < 32) {
    const int b = t;
    #pragma unroll
    for (int c = 0; c < 3; ++c) {
      float s3 = b3[p * 3 + c];
      const float* w3 = W3 + (size_t)(p * 3 + c) * 8;
      #pragma unroll
      for (int j = 0; j < 8; ++j) s3 += w3[j] * h2s[j][b];
      out[(size_t)(b * 3 + c) * NUM_POINTS + p] = s3;
    }
  }
}

extern "C" void kernel_launch(void* const* d_in, const int* in_sizes, int n_in,
                              void* d_out, int out_size, void* d_ws, size_t ws_size,
                              hipStream_t stream) {
  const float* glf = (const float*)d_in[0];
  const float* W1  = (const float*)d_in[1];
  const float* b1  = (const float*)d_in[2];
  const float* W2  = (const float*)d_in[3];
  const float* b2  = (const float*)d_in[4];
  const float* W3  = (const float*)d_in[5];
  const float* b3  = (const float*)d_in[6];
  float* out = (float*)d_out;
  short* frag = (short*)d_ws;  // 32 KB of bf16 B-fragments

  hipLaunchKernelGGL(build_bfrag, dim3(64), dim3(256), 0, stream, glf, frag);
  hipLaunchKernelGGL(fcdec_main, dim3(NUM_POINTS), dim3(256), 0, stream,
                     W1, b1, W2, b2, W3, b3, frag, out);
}